// Round 4
// baseline (575.511 us; speedup 1.0000x reference)
//
#include <hip/hip_runtime.h>
#include <hip/hip_bf16.h>

using f32x4  = __attribute__((ext_vector_type(4))) float;
using short8 = __attribute__((ext_vector_type(8))) short;
using bf16   = __hip_bfloat16;

constexpr int BATCH = 16;
constexpr int CH    = 256;
constexpr int HH    = 80;
constexpr int WW    = 80;
constexpr int NPIX  = HH * WW;   // 6400

__device__ __forceinline__ float b2f(unsigned short u) {
    union { unsigned int i; float f; } x;
    x.i = ((unsigned int)u) << 16;
    return x.f;
}

// global -> LDS direct copy, 16B per lane. Integer casts avoid addrspacecast
// legality questions: as(3) ptr = low 32 bits of generic LDS address.
typedef __attribute__((address_space(3))) void  lds_void;
typedef __attribute__((address_space(1))) const void glb_void;
__device__ __forceinline__ void glds16(const void* g, void* l) {
    __builtin_amdgcn_global_load_lds((glb_void*)(unsigned long long)g,
                                     (lds_void*)(unsigned int)(unsigned long long)l,
                                     16, 0, 0);
}

// ---------------------------------------------------------------------------
// Kernel 0: convert weights fp32 -> bf16.
// ---------------------------------------------------------------------------
__global__ __launch_bounds__(256) void convert_w(
    const float* __restrict__ Wq, const float* __restrict__ Wk,
    const float* __restrict__ Wv, bf16* __restrict__ Wb)
{
    const int elem = blockIdx.x * 256 + threadIdx.x;
    const int mat  = blockIdx.y;
    const float* src = (mat == 0) ? Wq : (mat == 1) ? Wk : Wv;
    Wb[(size_t)mat * CH * CH + elem] = __float2bfloat16(src[elem]);
}

// ---------------------------------------------------------------------------
// Kernel 1: x [b][c][n] fp32 -> x_t [bl][n][c] bf16 (tiled transpose)
// ---------------------------------------------------------------------------
__global__ __launch_bounds__(256) void transpose_cast(
    const float* __restrict__ x, bf16* __restrict__ xt, int b0)
{
    __shared__ float t[64][65];
    const int b  = b0 + blockIdx.z;
    const int n0 = blockIdx.x * 64;
    const int c0 = blockIdx.y * 64;
    const float* xb = x + (size_t)b * CH * NPIX;
    const int tid = threadIdx.x;

    {
        const int nl  = tid & 63;
        const int cl0 = tid >> 6;
        #pragma unroll
        for (int i = 0; i < 16; ++i) {
            const int cl = cl0 + i * 4;
            t[cl][nl] = xb[(size_t)(c0 + cl) * NPIX + n0 + nl];
        }
    }
    __syncthreads();
    {
        bf16* xtb = xt + (size_t)blockIdx.z * NPIX * CH;
        const int cl  = tid & 63;
        const int nl0 = tid >> 6;
        #pragma unroll
        for (int i = 0; i < 16; ++i) {
            const int nl = nl0 + i * 4;
            xtb[(size_t)(n0 + nl) * CH + c0 + cl] = __float2bfloat16(t[cl][nl]);
        }
    }
}

// ---------------------------------------------------------------------------
// Kernel 2: MFMA GEMM via global_load_lds + XOR-swizzle + LDS double-buffer.
// out[n][o] = sum_c xt[n][c] * W[o][c] (+bias)
// q,k: bf16 [bl][n][o] (swapped mfma operands -> packed ushort4 along o).
// v:   bf16 [bl][o][n].
// grid (NPIX/128, CH/128, cnb*3)  block 256 (4 waves, each 64x64)
//
// LDS layout: rows of 64B (BK=32 bf16), chunk (16B unit) swizzled by
// chunk' = chunk ^ ((row>>1)&3).  glds dest is linear; the global SOURCE
// address is pre-swizzled with the same involution; ds_read applies it too.
// Banks for a 16-lane frag read (rows r..r+15, fixed lk): 2-way only (free).
// ---------------------------------------------------------------------------
__global__ __launch_bounds__(256, 4) void qkv_mfma(
    const bf16* __restrict__ xt, const bf16* __restrict__ Wb,
    const float* __restrict__ bq, const float* __restrict__ bk,
    const float* __restrict__ bv,
    bf16* __restrict__ qo, bf16* __restrict__ ko, bf16* __restrict__ vt)
{
    const int m  = blockIdx.z % 3;
    const int bl = blockIdx.z / 3;
    const int n0 = blockIdx.x * 128;
    const int o0 = blockIdx.y * 128;
    const bf16*  W    = Wb + (size_t)m * CH * CH;
    const float* bias = (m == 0) ? bq : (m == 1) ? bk : bv;
    const bf16*  A    = xt + (size_t)bl * NPIX * CH;

    __shared__ char As[2][128 * 64];   // 8 KB per buffer
    __shared__ char Bs[2][128 * 64];   // 8 KB per buffer

    const int tid = threadIdx.x;
    const int wv  = tid >> 6, ln = tid & 63;
    const int wr  = wv >> 1,  wc = wv & 1;
    const int lm  = ln & 15,  lk = ln >> 4;

    f32x4 acc[4][4];
    #pragma unroll
    for (int i = 0; i < 4; ++i)
        #pragma unroll
        for (int j = 0; j < 4; ++j)
            #pragma unroll
            for (int r = 0; r < 4; ++r) acc[i][j][r] = 0.f;

    // stage one K-tile (BK=32) into buffer `buf` via global_load_lds
    auto stage = [&](int buf, int k0) {
        #pragma unroll
        for (int it = 0; it < 2; ++it) {
            const int idx = it * 256 + tid;          // 0..511
            const int row = idx >> 2;                // 0..127
            const int pos = idx & 3;                 // 16B slot in LDS row
            const int chk = pos ^ ((row >> 1) & 3);  // pre-swizzled source
            glds16(A + (size_t)(n0 + row) * CH + k0 + chk * 8, &As[buf][idx * 16]);
            glds16(W + (size_t)(o0 + row) * CH + k0 + chk * 8, &Bs[buf][idx * 16]);
        }
    };

    stage(0, 0);
    int buf = 0;
    #pragma unroll
    for (int t = 0; t < 8; ++t) {
        __syncthreads();                     // drains vmcnt -> buf ready
        if (t < 7) stage(buf ^ 1, (t + 1) * 32);   // prefetch flies under compute

        short8 afr[4], bfr[4];
        #pragma unroll
        for (int i = 0; i < 4; ++i) {
            const int row = wr * 64 + i * 16 + lm;
            const int chk = lk ^ ((row >> 1) & 3);
            afr[i] = *(const short8*)&As[buf][row * 64 + chk * 16];
        }
        #pragma unroll
        for (int j = 0; j < 4; ++j) {
            const int row = wc * 64 + j * 16 + lm;
            const int chk = lk ^ ((row >> 1) & 3);
            bfr[j] = *(const short8*)&Bs[buf][row * 64 + chk * 16];
        }
        if (m < 2) {
            #pragma unroll
            for (int i = 0; i < 4; ++i)
                #pragma unroll
                for (int j = 0; j < 4; ++j)
                    acc[i][j] = __builtin_amdgcn_mfma_f32_16x16x32_bf16(
                        bfr[j], afr[i], acc[i][j], 0, 0, 0);
        } else {
            #pragma unroll
            for (int i = 0; i < 4; ++i)
                #pragma unroll
                for (int j = 0; j < 4; ++j)
                    acc[i][j] = __builtin_amdgcn_mfma_f32_16x16x32_bf16(
                        afr[i], bfr[j], acc[i][j], 0, 0, 0);
        }
        buf ^= 1;
    }

    if (m < 2) {
        // Swapped: D row(reg dim) = o, col(lane&15) = n.
        bf16* out = (m == 0 ? qo : ko) + (size_t)bl * NPIX * CH;
        #pragma unroll
        for (int j = 0; j < 4; ++j) {
            const int ob = o0 + wc * 64 + j * 16 + lk * 4;
            const float4 b4 = *(const float4*)(bias + ob);
            #pragma unroll
            for (int i = 0; i < 4; ++i) {
                const int n = n0 + wr * 64 + i * 16 + lm;
                ushort4 pk;
                {
                    const bf16 h0 = __float2bfloat16(acc[i][j][0] + b4.x);
                    const bf16 h1 = __float2bfloat16(acc[i][j][1] + b4.y);
                    const bf16 h2 = __float2bfloat16(acc[i][j][2] + b4.z);
                    const bf16 h3 = __float2bfloat16(acc[i][j][3] + b4.w);
                    pk.x = *(const unsigned short*)&h0;
                    pk.y = *(const unsigned short*)&h1;
                    pk.z = *(const unsigned short*)&h2;
                    pk.w = *(const unsigned short*)&h3;
                }
                *(ushort4*)(out + (size_t)n * CH + ob) = pk;
            }
        }
    } else {
        // Normal: D row(reg dim) = n, col(lane&15) = o.  vt layout [o][n].
        bf16* out = vt + (size_t)bl * CH * NPIX;
        #pragma unroll
        for (int j = 0; j < 4; ++j) {
            const int o = o0 + wc * 64 + j * 16 + lm;
            const float bs = bias[o];
            #pragma unroll
            for (int i = 0; i < 4; ++i) {
                const int nb = n0 + wr * 64 + i * 16 + lk * 4;
                ushort4 pk;
                #pragma unroll
                for (int r = 0; r < 4; ++r) {
                    const bf16 h = __float2bfloat16(acc[i][j][r] + bs);
                    ((unsigned short*)&pk)[r] = *(const unsigned short*)&h;
                }
                *(ushort4*)(out + (size_t)o * NPIX + nb) = pk;
            }
        }
    }
}

// ---------------------------------------------------------------------------
// Kernel 3: scores (SoA planes) + output0.
// scores[bl][j][n] = dot_c(q[n][:], k[nbr(n,j)][:])
// grid (NPIX/4, cnb)  block 256 (wave per pixel)
// ---------------------------------------------------------------------------
__global__ __launch_bounds__(256) void scores_kernel(
    const bf16* __restrict__ q, const bf16* __restrict__ k,
    float* __restrict__ scores, float* __restrict__ out0, int b0)
{
    const int wave = threadIdx.x >> 6, lane = threadIdx.x & 63;
    const int n  = blockIdx.x * 4 + wave;
    const int bl = blockIdx.y;
    const int b  = b0 + bl;

    const unsigned short* qrow = (const unsigned short*)(q + ((size_t)bl * NPIX + n) * CH) + lane * 4;
    const unsigned short* kb   = (const unsigned short*)(k + (size_t)bl * NPIX * CH);

    const ushort4 qu = *(const ushort4*)qrow;
    const float q0 = b2f(qu.x), q1 = b2f(qu.y), q2 = b2f(qu.z), q3 = b2f(qu.w);

    const int r = n / WW, col = n % WW;
    float s[9], ssum = 0.f;
    #pragma unroll
    for (int j = 0; j < 9; ++j) {
        const int rr = min(max(r + j / 3 - 1, 0), HH - 1);
        const int c2 = min(max(col + j % 3 - 1, 0), WW - 1);
        const int nbr = rr * WW + c2;
        const ushort4 kv = *(const ushort4*)(kb + (size_t)nbr * CH + lane * 4);
        float d = q0 * b2f(kv.x) + q1 * b2f(kv.y) + q2 * b2f(kv.z) + q3 * b2f(kv.w);
        #pragma unroll
        for (int off = 32; off >= 1; off >>= 1) d += __shfl_xor(d, off, 64);
        s[j] = d;
        ssum += d;
    }
    if (lane == 0) {
        float* sp = scores + (size_t)bl * 9 * NPIX;
        #pragma unroll
        for (int j = 0; j < 9; ++j) sp[(size_t)j * NPIX + n] = s[j];
        const float center = s[4];
        out0[((size_t)b * NPIX + n) * 2 + 0] = center;
        out0[((size_t)b * NPIX + n) * 2 + 1] = (ssum - center) * 0.125f;
    }
}

// ---------------------------------------------------------------------------
// Kernel 4: fused new_v gather + residual + LayerNorm -> x_out.
// Block = one (b,c).  vt row (12.8 KB) staged in LDS; 4 px/thread x 5 iters.
// grid (CH, cnb)  block 320 (5 waves)
// ---------------------------------------------------------------------------
__global__ __launch_bounds__(320) void newv_ln(
    const float* __restrict__ x, const bf16* __restrict__ vt,
    const float* __restrict__ scores, float* __restrict__ xout, int b0)
{
    __shared__ __align__(16) unsigned short lds_v[NPIX];
    __shared__ float rsum[5], rsq[5];

    const int c  = blockIdx.x;
    const int bl = blockIdx.y;
    const int b  = b0 + bl;
    const int tid = threadIdx.x;

    const unsigned short* vrow = (const unsigned short*)(vt + ((size_t)bl * CH + c) * NPIX);
    const float* xrow = x + ((size_t)b * CH + c) * NPIX;
    const float* sb   = scores + (size_t)bl * 9 * NPIX;

    #pragma unroll
    for (int i = 0; i < 3; ++i) {
        const int t = tid + i * 320;
        if (t < NPIX / 8) ((int4*)lds_v)[t] = ((const int4*)vrow)[t];
    }
    __syncthreads();

    float val[20];
    float sum = 0.f, sq = 0.f;
    #pragma unroll
    for (int it = 0; it < 5; ++it) {
        const int p   = tid + it * 320;
        const int n0  = p * 4;
        const int r   = p / 20;
        const int c0  = (p % 20) * 4;

        const int rm = max(r - 1, 0) * WW;
        const int r0 = r * WW;
        const int rp = min(r + 1, HH - 1) * WW;

        float4 s[9];
        #pragma unroll
        for (int j = 0; j < 9; ++j)
            s[j] = *(const float4*)(sb + (size_t)j * NPIX + n0);

        const float4 xin = *(const float4*)(xrow + n0);

        const int cA = max(c0 - 1, 0);
        const int cF = min(c0 + 4, WW - 1);
        float vm[6], v0[6], vp[6];
        vm[0] = b2f(lds_v[rm + cA]); v0[0] = b2f(lds_v[r0 + cA]); vp[0] = b2f(lds_v[rp + cA]);
        #pragma unroll
        for (int t = 1; t < 5; ++t) {
            vm[t] = b2f(lds_v[rm + c0 + t - 1]);
            v0[t] = b2f(lds_v[r0 + c0 + t - 1]);
            vp[t] = b2f(lds_v[rp + c0 + t - 1]);
        }
        vm[5] = b2f(lds_v[rm + cF]); v0[5] = b2f(lds_v[r0 + cF]); vp[5] = b2f(lds_v[rp + cF]);

        #pragma unroll
        for (int px = 0; px < 4; ++px) {
            const float sc0 = ((const float*)&s[0])[px];
            const float sc1 = ((const float*)&s[1])[px];
            const float sc2 = ((const float*)&s[2])[px];
            const float sc3 = ((const float*)&s[3])[px];
            const float sc4 = ((const float*)&s[4])[px];
            const float sc5 = ((const float*)&s[5])[px];
            const float sc6 = ((const float*)&s[6])[px];
            const float sc7 = ((const float*)&s[7])[px];
            const float sc8 = ((const float*)&s[8])[px];
            float a;
            a  = sc0 * vm[px] + sc1 * vm[px + 1] + sc2 * vm[px + 2];
            a += sc3 * v0[px] + sc4 * v0[px + 1] + sc5 * v0[px + 2];
            a += sc6 * vp[px] + sc7 * vp[px + 1] + sc8 * vp[px + 2];
            const float vv = ((const float*)&xin)[px] + a;
            val[it * 4 + px] = vv;
            sum += vv;
            sq  += vv * vv;
        }
    }

    #pragma unroll
    for (int off = 32; off >= 1; off >>= 1) {
        sum += __shfl_xor(sum, off, 64);
        sq  += __shfl_xor(sq,  off, 64);
    }
    const int wave = tid >> 6, lane = tid & 63;
    if (lane == 0) { rsum[wave] = sum; rsq[wave] = sq; }
    __syncthreads();
    sum = rsum[0] + rsum[1] + rsum[2] + rsum[3] + rsum[4];
    sq  = rsq[0]  + rsq[1]  + rsq[2]  + rsq[3]  + rsq[4];

    const float mu   = sum * (1.f / NPIX);
    const float var  = sq * (1.f / NPIX) - mu * mu;
    const float rstd = rsqrtf(var + 1e-5f);

    float* orow = xout + ((size_t)b * CH + c) * NPIX;
    #pragma unroll
    for (int it = 0; it < 5; ++it) {
        const int n0 = (tid + it * 320) * 4;
        float4 o;
        o.x = (val[it * 4 + 0] - mu) * rstd;
        o.y = (val[it * 4 + 1] - mu) * rstd;
        o.z = (val[it * 4 + 2] - mu) * rstd;
        o.w = (val[it * 4 + 3] - mu) * rstd;
        *(float4*)(orow + n0) = o;
    }
}

// ---------------------------------------------------------------------------
extern "C" void kernel_launch(void* const* d_in, const int* in_sizes, int n_in,
                              void* d_out, int out_size, void* d_ws, size_t ws_size,
                              hipStream_t stream)
{
    const float* x  = (const float*)d_in[0];
    const float* Wq = (const float*)d_in[1];
    const float* bq = (const float*)d_in[2];
    const float* Wk = (const float*)d_in[3];
    const float* bk = (const float*)d_in[4];
    const float* Wv = (const float*)d_in[5];
    const float* bv = (const float*)d_in[6];

    float* out0 = (float*)d_out;                       // [B][N][2]
    float* xout = out0 + (size_t)BATCH * NPIX * 2;     // [B][C][N]

    char* ws = (char*)d_ws;
    bf16* Wb = (bf16*)ws;
    ws += (size_t)3 * CH * CH * sizeof(bf16);          // 384 KiB

    const size_t fBF = (size_t)NPIX * CH * sizeof(bf16);   // 3.28 MB
    const size_t fSC = (size_t)NPIX * 9 * sizeof(float);   // 230 KB
    const size_t perBatch = 4 * fBF + fSC;                 // ~13.3 MB

    size_t avail = ws_size - ((size_t)3 * CH * CH * sizeof(bf16));
    int NB = (int)(avail / perBatch);
    if (NB < 1)  NB = 1;
    if (NB > BATCH) NB = BATCH;

    bf16*  xt  = (bf16*)ws;
    bf16*  qb  = (bf16*)(ws + (size_t)NB * fBF);
    bf16*  kb  = (bf16*)(ws + (size_t)NB * fBF * 2);
    bf16*  vt  = (bf16*)(ws + (size_t)NB * fBF * 3);
    float* sc  = (float*)(ws + (size_t)NB * fBF * 4);

    convert_w<<<dim3(CH * CH / 256, 3), 256, 0, stream>>>(Wq, Wk, Wv, Wb);

    for (int b0 = 0; b0 < BATCH; b0 += NB) {
        const int cnb = (BATCH - b0 < NB) ? (BATCH - b0) : NB;

        transpose_cast<<<dim3(NPIX / 64, CH / 64, cnb), 256, 0, stream>>>(x, xt, b0);

        qkv_mfma<<<dim3(NPIX / 128, CH / 128, cnb * 3), 256, 0, stream>>>(
            xt, Wb, bq, bk, bv, qb, kb, vt);

        scores_kernel<<<dim3(NPIX / 4, cnb), 256, 0, stream>>>(qb, kb, sc, out0, b0);

        newv_ln<<<dim3(CH, cnb), 320, 0, stream>>>(x, vt, sc, xout, b0);
    }
}

// Round 5
// 280.996 us; speedup vs baseline: 2.0481x; 2.0481x over previous
//
#include <hip/hip_runtime.h>
#include <hip/hip_bf16.h>

using f32x4  = __attribute__((ext_vector_type(4))) float;
using short8 = __attribute__((ext_vector_type(8))) short;
using bf16   = __hip_bfloat16;

constexpr int BATCH = 16;
constexpr int CH    = 256;
constexpr int HH    = 80;
constexpr int WW    = 80;
constexpr int NPIX  = HH * WW;   // 6400

__device__ __forceinline__ float b2f(unsigned short u) {
    union { unsigned int i; float f; } x;
    x.i = ((unsigned int)u) << 16;
    return x.f;
}

// global -> LDS direct copy, 16B per lane.
typedef __attribute__((address_space(3))) void  lds_void;
typedef __attribute__((address_space(1))) const void glb_void;
__device__ __forceinline__ void glds16(const void* g, void* l) {
    __builtin_amdgcn_global_load_lds((glb_void*)(unsigned long long)g,
                                     (lds_void*)(unsigned int)(unsigned long long)l,
                                     16, 0, 0);
}

// ---------------------------------------------------------------------------
// Kernel 0: convert weights fp32 -> bf16.
// ---------------------------------------------------------------------------
__global__ __launch_bounds__(256) void convert_w(
    const float* __restrict__ Wq, const float* __restrict__ Wk,
    const float* __restrict__ Wv, bf16* __restrict__ Wb)
{
    const int elem = blockIdx.x * 256 + threadIdx.x;
    const int mat  = blockIdx.y;
    const float* src = (mat == 0) ? Wq : (mat == 1) ? Wk : Wv;
    Wb[(size_t)mat * CH * CH + elem] = __float2bfloat16(src[elem]);
}

// ---------------------------------------------------------------------------
// Kernel 1: x [b][c][n] fp32 -> x_t [bl][n][c] bf16 (tiled transpose)
// ---------------------------------------------------------------------------
__global__ __launch_bounds__(256) void transpose_cast(
    const float* __restrict__ x, bf16* __restrict__ xt, int b0)
{
    __shared__ float t[64][65];
    const int b  = b0 + blockIdx.z;
    const int n0 = blockIdx.x * 64;
    const int c0 = blockIdx.y * 64;
    const float* xb = x + (size_t)b * CH * NPIX;
    const int tid = threadIdx.x;

    {
        const int nl  = tid & 63;
        const int cl0 = tid >> 6;
        #pragma unroll
        for (int i = 0; i < 16; ++i) {
            const int cl = cl0 + i * 4;
            t[cl][nl] = xb[(size_t)(c0 + cl) * NPIX + n0 + nl];
        }
    }
    __syncthreads();
    {
        bf16* xtb = xt + (size_t)blockIdx.z * NPIX * CH;
        const int cl  = tid & 63;
        const int nl0 = tid >> 6;
        #pragma unroll
        for (int i = 0; i < 16; ++i) {
            const int nl = nl0 + i * 4;
            xtb[(size_t)(n0 + nl) * CH + c0 + cl] = __float2bfloat16(t[cl][nl]);
        }
    }
}

// ---------------------------------------------------------------------------
// Kernel 2: MFMA GEMM via global_load_lds + XOR-swizzle + LDS double-buffer.
// __launch_bounds__(256, 2): VGPR cap 256 -> NO spill (r4 lesson: (256,4)
// capped VGPR at 128, spilled acc -> 1.17 GB scratch write traffic).
// grid (NPIX/128, CH/128, cnb*3)  block 256 (4 waves, each 64x64)
// ---------------------------------------------------------------------------
__global__ __launch_bounds__(256, 2) void qkv_mfma(
    const bf16* __restrict__ xt, const bf16* __restrict__ Wb,
    const float* __restrict__ bq, const float* __restrict__ bk,
    const float* __restrict__ bv,
    bf16* __restrict__ qo, bf16* __restrict__ ko, bf16* __restrict__ vt)
{
    const int m  = blockIdx.z % 3;
    const int bl = blockIdx.z / 3;
    const int n0 = blockIdx.x * 128;
    const int o0 = blockIdx.y * 128;
    const bf16*  W    = Wb + (size_t)m * CH * CH;
    const float* bias = (m == 0) ? bq : (m == 1) ? bk : bv;
    const bf16*  A    = xt + (size_t)bl * NPIX * CH;

    __shared__ char As[2][128 * 64];   // 8 KB per buffer
    __shared__ char Bs[2][128 * 64];

    const int tid = threadIdx.x;
    const int wv  = tid >> 6, ln = tid & 63;
    const int wr  = wv >> 1,  wc = wv & 1;
    const int lm  = ln & 15,  lk = ln >> 4;

    f32x4 acc[4][4];
    #pragma unroll
    for (int i = 0; i < 4; ++i)
        #pragma unroll
        for (int j = 0; j < 4; ++j)
            #pragma unroll
            for (int r = 0; r < 4; ++r) acc[i][j][r] = 0.f;

    auto stage = [&](int buf, int k0) {
        #pragma unroll
        for (int it = 0; it < 2; ++it) {
            const int idx = it * 256 + tid;          // 0..511
            const int row = idx >> 2;                // 0..127
            const int pos = idx & 3;                 // 16B slot in LDS row
            const int chk = pos ^ ((row >> 1) & 3);  // pre-swizzled source
            glds16(A + (size_t)(n0 + row) * CH + k0 + chk * 8, &As[buf][idx * 16]);
            glds16(W + (size_t)(o0 + row) * CH + k0 + chk * 8, &Bs[buf][idx * 16]);
        }
    };

    stage(0, 0);
    int buf = 0;
    #pragma unroll
    for (int t = 0; t < 8; ++t) {
        __syncthreads();                           // drains vmcnt -> buf ready
        if (t < 7) stage(buf ^ 1, (t + 1) * 32);   // prefetch flies under compute

        short8 afr[4], bfr[4];
        #pragma unroll
        for (int i = 0; i < 4; ++i) {
            const int row = wr * 64 + i * 16 + lm;
            const int chk = lk ^ ((row >> 1) & 3);
            afr[i] = *(const short8*)&As[buf][row * 64 + chk * 16];
        }
        #pragma unroll
        for (int j = 0; j < 4; ++j) {
            const int row = wc * 64 + j * 16 + lm;
            const int chk = lk ^ ((row >> 1) & 3);
            bfr[j] = *(const short8*)&Bs[buf][row * 64 + chk * 16];
        }
        if (m < 2) {
            #pragma unroll
            for (int i = 0; i < 4; ++i)
                #pragma unroll
                for (int j = 0; j < 4; ++j)
                    acc[i][j] = __builtin_amdgcn_mfma_f32_16x16x32_bf16(
                        bfr[j], afr[i], acc[i][j], 0, 0, 0);
        } else {
            #pragma unroll
            for (int i = 0; i < 4; ++i)
                #pragma unroll
                for (int j = 0; j < 4; ++j)
                    acc[i][j] = __builtin_amdgcn_mfma_f32_16x16x32_bf16(
                        afr[i], bfr[j], acc[i][j], 0, 0, 0);
        }
        buf ^= 1;
    }

    if (m < 2) {
        // Swapped: D row(reg dim) = o, col(lane&15) = n.
        bf16* out = (m == 0 ? qo : ko) + (size_t)bl * NPIX * CH;
        #pragma unroll
        for (int j = 0; j < 4; ++j) {
            const int ob = o0 + wc * 64 + j * 16 + lk * 4;
            const float4 b4 = *(const float4*)(bias + ob);
            #pragma unroll
            for (int i = 0; i < 4; ++i) {
                const int n = n0 + wr * 64 + i * 16 + lm;
                ushort4 pk;
                {
                    const bf16 h0 = __float2bfloat16(acc[i][j][0] + b4.x);
                    const bf16 h1 = __float2bfloat16(acc[i][j][1] + b4.y);
                    const bf16 h2 = __float2bfloat16(acc[i][j][2] + b4.z);
                    const bf16 h3 = __float2bfloat16(acc[i][j][3] + b4.w);
                    pk.x = *(const unsigned short*)&h0;
                    pk.y = *(const unsigned short*)&h1;
                    pk.z = *(const unsigned short*)&h2;
                    pk.w = *(const unsigned short*)&h3;
                }
                *(ushort4*)(out + (size_t)n * CH + ob) = pk;
            }
        }
    } else {
        // Normal: D row(reg dim) = n, col(lane&15) = o.  vt layout [o][n].
        bf16* out = vt + (size_t)bl * CH * NPIX;
        #pragma unroll
        for (int j = 0; j < 4; ++j) {
            const int o = o0 + wc * 64 + j * 16 + lm;
            const float bs = bias[o];
            #pragma unroll
            for (int i = 0; i < 4; ++i) {
                const int nb = n0 + wr * 64 + i * 16 + lk * 4;
                ushort4 pk;
                #pragma unroll
                for (int r = 0; r < 4; ++r) {
                    const bf16 h = __float2bfloat16(acc[i][j][r] + bs);
                    ((unsigned short*)&pk)[r] = *(const unsigned short*)&h;
                }
                *(ushort4*)(out + (size_t)o * NPIX + nb) = pk;
            }
        }
    }
}

// ---------------------------------------------------------------------------
// Kernel 3: scores (SoA planes) + output0.
// grid (NPIX/4, cnb)  block 256 (wave per pixel)
// ---------------------------------------------------------------------------
__global__ __launch_bounds__(256) void scores_kernel(
    const bf16* __restrict__ q, const bf16* __restrict__ k,
    float* __restrict__ scores, float* __restrict__ out0, int b0)
{
    const int wave = threadIdx.x >> 6, lane = threadIdx.x & 63;
    const int n  = blockIdx.x * 4 + wave;
    const int bl = blockIdx.y;
    const int b  = b0 + bl;

    const unsigned short* qrow = (const unsigned short*)(q + ((size_t)bl * NPIX + n) * CH) + lane * 4;
    const unsigned short* kb   = (const unsigned short*)(k + (size_t)bl * NPIX * CH);

    const ushort4 qu = *(const ushort4*)qrow;
    const float q0 = b2f(qu.x), q1 = b2f(qu.y), q2 = b2f(qu.z), q3 = b2f(qu.w);

    const int r = n / WW, col = n % WW;
    float s[9], ssum = 0.f;
    #pragma unroll
    for (int j = 0; j < 9; ++j) {
        const int rr = min(max(r + j / 3 - 1, 0), HH - 1);
        const int c2 = min(max(col + j % 3 - 1, 0), WW - 1);
        const int nbr = rr * WW + c2;
        const ushort4 kv = *(const ushort4*)(kb + (size_t)nbr * CH + lane * 4);
        float d = q0 * b2f(kv.x) + q1 * b2f(kv.y) + q2 * b2f(kv.z) + q3 * b2f(kv.w);
        #pragma unroll
        for (int off = 32; off >= 1; off >>= 1) d += __shfl_xor(d, off, 64);
        s[j] = d;
        ssum += d;
    }
    if (lane == 0) {
        float* sp = scores + (size_t)bl * 9 * NPIX;
        #pragma unroll
        for (int j = 0; j < 9; ++j) sp[(size_t)j * NPIX + n] = s[j];
        const float center = s[4];
        out0[((size_t)b * NPIX + n) * 2 + 0] = center;
        out0[((size_t)b * NPIX + n) * 2 + 1] = (ssum - center) * 0.125f;
    }
}

// ---------------------------------------------------------------------------
// Kernel 4: fused new_v gather + residual + LayerNorm -> x_out.
// grid (CH, cnb)  block 320 (5 waves)
// ---------------------------------------------------------------------------
__global__ __launch_bounds__(320) void newv_ln(
    const float* __restrict__ x, const bf16* __restrict__ vt,
    const float* __restrict__ scores, float* __restrict__ xout, int b0)
{
    __shared__ __align__(16) unsigned short lds_v[NPIX];
    __shared__ float rsum[5], rsq[5];

    const int c  = blockIdx.x;
    const int bl = blockIdx.y;
    const int b  = b0 + bl;
    const int tid = threadIdx.x;

    const unsigned short* vrow = (const unsigned short*)(vt + ((size_t)bl * CH + c) * NPIX);
    const float* xrow = x + ((size_t)b * CH + c) * NPIX;
    const float* sb   = scores + (size_t)bl * 9 * NPIX;

    #pragma unroll
    for (int i = 0; i < 3; ++i) {
        const int t = tid + i * 320;
        if (t < NPIX / 8) ((int4*)lds_v)[t] = ((const int4*)vrow)[t];
    }
    __syncthreads();

    float val[20];
    float sum = 0.f, sq = 0.f;
    #pragma unroll
    for (int it = 0; it < 5; ++it) {
        const int p   = tid + it * 320;
        const int n0  = p * 4;
        const int r   = p / 20;
        const int c0  = (p % 20) * 4;

        const int rm = max(r - 1, 0) * WW;
        const int r0 = r * WW;
        const int rp = min(r + 1, HH - 1) * WW;

        float4 s[9];
        #pragma unroll
        for (int j = 0; j < 9; ++j)
            s[j] = *(const float4*)(sb + (size_t)j * NPIX + n0);

        const float4 xin = *(const float4*)(xrow + n0);

        const int cA = max(c0 - 1, 0);
        const int cF = min(c0 + 4, WW - 1);
        float vm[6], v0[6], vp[6];
        vm[0] = b2f(lds_v[rm + cA]); v0[0] = b2f(lds_v[r0 + cA]); vp[0] = b2f(lds_v[rp + cA]);
        #pragma unroll
        for (int t = 1; t < 5; ++t) {
            vm[t] = b2f(lds_v[rm + c0 + t - 1]);
            v0[t] = b2f(lds_v[r0 + c0 + t - 1]);
            vp[t] = b2f(lds_v[rp + c0 + t - 1]);
        }
        vm[5] = b2f(lds_v[rm + cF]); v0[5] = b2f(lds_v[r0 + cF]); vp[5] = b2f(lds_v[rp + cF]);

        #pragma unroll
        for (int px = 0; px < 4; ++px) {
            const float sc0 = ((const float*)&s[0])[px];
            const float sc1 = ((const float*)&s[1])[px];
            const float sc2 = ((const float*)&s[2])[px];
            const float sc3 = ((const float*)&s[3])[px];
            const float sc4 = ((const float*)&s[4])[px];
            const float sc5 = ((const float*)&s[5])[px];
            const float sc6 = ((const float*)&s[6])[px];
            const float sc7 = ((const float*)&s[7])[px];
            const float sc8 = ((const float*)&s[8])[px];
            float a;
            a  = sc0 * vm[px] + sc1 * vm[px + 1] + sc2 * vm[px + 2];
            a += sc3 * v0[px] + sc4 * v0[px + 1] + sc5 * v0[px + 2];
            a += sc6 * vp[px] + sc7 * vp[px + 1] + sc8 * vp[px + 2];
            const float vv = ((const float*)&xin)[px] + a;
            val[it * 4 + px] = vv;
            sum += vv;
            sq  += vv * vv;
        }
    }

    #pragma unroll
    for (int off = 32; off >= 1; off >>= 1) {
        sum += __shfl_xor(sum, off, 64);
        sq  += __shfl_xor(sq,  off, 64);
    }
    const int wave = tid >> 6, lane = tid & 63;
    if (lane == 0) { rsum[wave] = sum; rsq[wave] = sq; }
    __syncthreads();
    sum = rsum[0] + rsum[1] + rsum[2] + rsum[3] + rsum[4];
    sq  = rsq[0]  + rsq[1]  + rsq[2]  + rsq[3]  + rsq[4];

    const float mu   = sum * (1.f / NPIX);
    const float var  = sq * (1.f / NPIX) - mu * mu;
    const float rstd = rsqrtf(var + 1e-5f);

    float* orow = xout + ((size_t)b * CH + c) * NPIX;
    #pragma unroll
    for (int it = 0; it < 5; ++it) {
        const int n0 = (tid + it * 320) * 4;
        float4 o;
        o.x = (val[it * 4 + 0] - mu) * rstd;
        o.y = (val[it * 4 + 1] - mu) * rstd;
        o.z = (val[it * 4 + 2] - mu) * rstd;
        o.w = (val[it * 4 + 3] - mu) * rstd;
        *(float4*)(orow + n0) = o;
    }
}

// ---------------------------------------------------------------------------
extern "C" void kernel_launch(void* const* d_in, const int* in_sizes, int n_in,
                              void* d_out, int out_size, void* d_ws, size_t ws_size,
                              hipStream_t stream)
{
    const float* x  = (const float*)d_in[0];
    const float* Wq = (const float*)d_in[1];
    const float* bq = (const float*)d_in[2];
    const float* Wk = (const float*)d_in[3];
    const float* bk = (const float*)d_in[4];
    const float* Wv = (const float*)d_in[5];
    const float* bv = (const float*)d_in[6];

    float* out0 = (float*)d_out;                       // [B][N][2]
    float* xout = out0 + (size_t)BATCH * NPIX * 2;     // [B][C][N]

    char* ws = (char*)d_ws;
    bf16* Wb = (bf16*)ws;
    ws += (size_t)3 * CH * CH * sizeof(bf16);          // 384 KiB

    const size_t fBF = (size_t)NPIX * CH * sizeof(bf16);   // 3.28 MB
    const size_t fSC = (size_t)NPIX * 9 * sizeof(float);   // 230 KB
    const size_t perBatch = 4 * fBF + fSC;                 // ~13.3 MB

    size_t avail = ws_size - ((size_t)3 * CH * CH * sizeof(bf16));
    int NB = (int)(avail / perBatch);
    if (NB < 1)  NB = 1;
    if (NB > BATCH) NB = BATCH;

    bf16*  xt  = (bf16*)ws;
    bf16*  qb  = (bf16*)(ws + (size_t)NB * fBF);
    bf16*  kb  = (bf16*)(ws + (size_t)NB * fBF * 2);
    bf16*  vt  = (bf16*)(ws + (size_t)NB * fBF * 3);
    float* sc  = (float*)(ws + (size_t)NB * fBF * 4);

    convert_w<<<dim3(CH * CH / 256, 3), 256, 0, stream>>>(Wq, Wk, Wv, Wb);

    for (int b0 = 0; b0 < BATCH; b0 += NB) {
        const int cnb = (BATCH - b0 < NB) ? (BATCH - b0) : NB;

        transpose_cast<<<dim3(NPIX / 64, CH / 64, cnb), 256, 0, stream>>>(x, xt, b0);

        qkv_mfma<<<dim3(NPIX / 128, CH / 128, cnb * 3), 256, 0, stream>>>(
            xt, Wb, bq, bk, bv, qb, kb, vt);

        scores_kernel<<<dim3(NPIX / 4, cnb), 256, 0, stream>>>(qb, kb, sc, out0, b0);

        newv_ln<<<dim3(CH, cnb), 320, 0, stream>>>(x, vt, sc, xout, b0);
    }
}